// Round 1
// 169.827 us; speedup vs baseline: 1.0823x; 1.0823x over previous
//
#include <hip/hip_runtime.h>
#include <math.h>

#define BB 8
#define CIN 256
#define COUT 256
#define HH 64
#define WW 64
#define OCM 27          // 18 offset + 9 mod channels
#define KTOT 2304       // tap-major: k = tap*256 + c
#define NKT 72          // K-tiles of 32

typedef unsigned int u32;
typedef unsigned short u16;
typedef _Float16 f16;

// ---------------- ws layout (bytes) ----------------
#define WS_XBF 0
#define WS_W2 16777216
#define WS_W2OM 17956864
#define WS_OFFMOD 18104320

__device__ __forceinline__ u16 f2h(float f) {
    f16 h = (f16)f;
    return __builtin_bit_cast(u16, h);
}

typedef __attribute__((address_space(1))) const unsigned int* gptr_t;
typedef __attribute__((address_space(3))) unsigned int* lptr_t;
__device__ __forceinline__ void gl2lds16(const void* g, void* l) {
    __builtin_amdgcn_global_load_lds((gptr_t)g, (lptr_t)l, 16, 0, 0);
}

typedef __attribute__((ext_vector_type(8))) f16 frag;   // 4 VGPR MFMA operand
typedef __attribute__((ext_vector_type(2))) f16 h2;     // packed-half pair
typedef __attribute__((ext_vector_type(4))) float f4;

// Swizzle g(row) = (row>>1)&3: conflict-free (2-way max) for BOTH the
// staging-write phase and the frag-read phase (16 consecutive rows, fixed oct).
__device__ __forceinline__ int sw_off(int row, int oct) {
    return (row << 5) + ((oct ^ ((row >> 1) & 3)) << 3);
}

#define BARRIER_RAW() do { asm volatile("" ::: "memory"); \
    __builtin_amdgcn_s_barrier(); asm volatile("" ::: "memory"); } while (0)

// K0: NCHW f32 -> NHWC f16 via LDS transpose; packed u32 writes.
__global__ __launch_bounds__(256) void k_nhwc3(const float* __restrict__ x,
                                               u16* __restrict__ xbf) {
    const int y = blockIdx.x, b = blockIdx.y;
    __shared__ float T[64][65];
    const int t = threadIdx.x;
    const int wl = t & 63, g = t >> 6;
    const int pr = wl & 31, wsub = wl >> 5;   // c-pair, w-subrow for write phase
    u32* xo = (u32*)xbf;
    for (int c0 = 0; c0 < 256; c0 += 64) {
#pragma unroll
        for (int i = 0; i < 16; ++i) {
            int c = g + i * 4;
            T[c][wl] = x[(((size_t)(b * 256 + c0 + c)) << 12) + (y << 6) + wl];
        }
        __syncthreads();
#pragma unroll
        for (int j = 0; j < 8; ++j) {
            int w = j * 8 + g * 2 + wsub;
            u32 v = (u32)f2h(T[2 * pr][w]) | ((u32)f2h(T[2 * pr + 1][w]) << 16);
            xo[((((size_t)b << 12) + (y << 6) + w) << 7) + (c0 >> 1) + pr] = v;
        }
        __syncthreads();
    }
}

// K0b: reg_w [n][c][tap] -> w2 [kt][n][32] f16, k = tap*256 + c
__global__ void k_pack_w2(const float* __restrict__ rw, u16* __restrict__ w2) {
    int o = blockIdx.x * blockDim.x + threadIdx.x;
    if (o >= NKT * COUT * 32) return;
    int kk = o & 31;
    int n = (o >> 5) & 255;
    int kt = o >> 13;
    int k = kt * 32 + kk;
    int tap = k >> 8;
    int c = k & 255;
    w2[o] = f2h(rw[n * KTOT + c * 9 + tap]);
}

// K0c: offset_w/mod_w -> w2om [kt][32 oc][32 kk] f16
__global__ void k_pack_w2om(const float* __restrict__ ow, const float* __restrict__ mw,
                            u16* __restrict__ w2om) {
    int o = blockIdx.x * blockDim.x + threadIdx.x;
    if (o >= NKT * 32 * 32) return;
    int kk = o & 31;
    int oc = (o >> 5) & 31;
    int kt = o >> 10;
    int k = kt * 32 + kk;
    int tap = k >> 8;
    int c = k & 255;
    float v = 0.f;
    if (oc < 18) v = ow[oc * KTOT + c * 9 + tap];
    else if (oc < 27) v = mw[(oc - 18) * KTOT + c * 9 + tap];
    w2om[o] = f2h(v);
}

// K1: offset/mod conv, pipelined MFMA, K split across wave-halves. f16 frags.
// grid: 512 linear, b = idx&7 (XCD-local batch), h = idx>>3.
__global__ __launch_bounds__(512, 4) void k_offmod6(
    const u16* __restrict__ xbf, const u16* __restrict__ w2om,
    const float* __restrict__ ob, const float* __restrict__ mb,
    float* __restrict__ offmod)
{
    const int b = blockIdx.x & 7, h = blockIdx.x >> 3;
    const int t = threadIdx.x;
    const int lane = t & 63, wv = t >> 6;
    const int hf = wv >> 2;         // K-half
    const int wl4 = wv & 3;
    const int th = t & 255;
    const int fr = lane & 15, q = lane >> 4;
    const int wm = wl4 << 4;
    const int mg = th >> 2, oct = th & 3;

    __shared__ u16 AsB[2][2][64 * 32];
    __shared__ u16 BsB[2][2][32 * 32];
    __shared__ float red[64][33];

    const u16* xb = xbf + ((size_t)b << 20);
    const int kbase = hf * 36;

    auto loadA = [&](int kt, uint4* r) {
        int tap = kt >> 3;
        int yy = h + tap / 3 - 1, xx = mg + tap % 3 - 1;
        int c0 = ((kt & 7) << 5) + (oct << 3);
        uint4 v = make_uint4(0, 0, 0, 0);
        if ((unsigned)yy < HH && (unsigned)xx < WW)
            v = *(const uint4*)(xb + (((size_t)yy << 6) + xx) * 256 + c0);
        *r = v;
    };
    auto loadB = [&](int kt, uint4* r) {
        if (th < 128) *r = *(const uint4*)(w2om + (size_t)kt * 1024 + (th >> 2) * 32 + (th & 3) * 8);
    };
    auto storeAB = [&](int buf, uint4* rA, uint4* rB) {
        *(uint4*)&AsB[hf][buf][sw_off(mg, oct)] = *rA;
        if (th < 128) *(uint4*)&BsB[hf][buf][sw_off(th >> 2, th & 3)] = *rB;
    };

    f4 acc[2];
    acc[0] = (f4){0.f, 0.f, 0.f, 0.f};
    acc[1] = (f4){0.f, 0.f, 0.f, 0.f};

    uint4 rA0, rB0, rA1, rB1;
    loadA(kbase, &rA0); loadB(kbase, &rB0);
    storeAB(0, &rA0, &rB0);
    loadA(kbase + 1, &rA1); loadB(kbase + 1, &rB1);
    asm volatile("s_waitcnt lgkmcnt(0)" ::: "memory");

    auto body = [&](int i, int p, uint4* cA, uint4* cB, uint4* nA, uint4* nB) {
        BARRIER_RAW();
        frag a  = *(const frag*)&AsB[hf][p][sw_off(wm + fr, q)];
        frag b0 = *(const frag*)&BsB[hf][p][sw_off(fr, q)];
        frag b1 = *(const frag*)&BsB[hf][p][sw_off(16 + fr, q)];
        if (i + 2 < 36) { loadA(kbase + i + 2, nA); loadB(kbase + i + 2, nB); }
        if (i + 1 < 36) storeAB(1 - p, cA, cB);
        acc[0] = __builtin_amdgcn_mfma_f32_16x16x32_f16(a, b0, acc[0], 0, 0, 0);
        acc[1] = __builtin_amdgcn_mfma_f32_16x16x32_f16(a, b1, acc[1], 0, 0, 0);
        asm volatile("s_waitcnt lgkmcnt(0)" ::: "memory");
    };
    for (int i = 0; i < 36; i += 2) {
        body(i, 0, &rA1, &rB1, &rA0, &rB0);
        body(i + 1, 1, &rA0, &rB0, &rA1, &rB1);
    }

    // ---- K-half reduction ----
    if (hf == 1) {
#pragma unroll
        for (int ni = 0; ni < 2; ++ni)
#pragma unroll
            for (int r = 0; r < 4; ++r)
                red[wm + q * 4 + r][ni * 16 + fr] = acc[ni][r];
    }
    __syncthreads();
    if (hf == 0) {
#pragma unroll
        for (int ni = 0; ni < 2; ++ni) {
            int oc = ni * 16 + fr;
            if (oc >= OCM) continue;
            bool is_off = oc < 18;
            float bias = is_off ? ob[oc] : mb[oc - 18];
            float4 v;
            float* vp = (float*)&v;
#pragma unroll
            for (int r = 0; r < 4; ++r) {
                float s = acc[ni][r] + red[wm + q * 4 + r][oc] + bias;
                vp[r] = is_off ? fminf(fmaxf(s, -16.f), 16.f)
                               : 1.f / (1.f + __expf(-s));
            }
            *(float4*)&offmod[(((size_t)b * OCM + oc) << 12) + (h << 6) + wm + q * 4] = v;
        }
    }
}

// K2: deformable conv, M=128 (2 h-rows), 8 consumer + 8 producer waves,
// f16 packed interp, packed sample table, distance-3 corner prefetch.
// grid: 256 linear, b = idx&7 (XCD-local batch), hpair = idx>>3.
__global__ __launch_bounds__(1024, 4) void k_deform8(
    const u16* __restrict__ xbf, const float* __restrict__ offmod,
    const u16* __restrict__ w2, float* __restrict__ out)
{
    const int t = threadIdx.x;
    const int b = blockIdx.x & 7, hp = blockIdx.x >> 3;
    const int h0 = hp << 1;
    const int lane = t & 63, wv = t >> 6;

    __shared__ uint4 STAB[9][128];      // {idx0..3 (u16), w0..3 (f16)} per (tap,m)
    __shared__ u16 AsB[2][128 * 32];
    __shared__ u16 BsB[2][256 * 32];

    // ---- sample tables: 9 taps x 128 m (all 1024 threads) ----
    const float* om = offmod + (size_t)b * OCM * 4096;
    for (int e = t; e < 9 * 128; e += 1024) {
        int m = e & 127, tap = e >> 7;
        int hh = h0 + (m >> 6), ww = m & 63;
        float dy = om[(tap * 2) * 4096 + hh * 64 + ww];
        float dx = om[(tap * 2 + 1) * 4096 + hh * 64 + ww];
        float mv = om[(18 + tap) * 4096 + hh * 64 + ww];
        float py = dy + (float)(tap / 3) + (float)(hh - 1);
        float px = dx + (float)(tap % 3) + (float)(ww - 1);
        float y0f = floorf(py), x0f = floorf(px);
        float ly = py - y0f, lx = px - x0f;
        int y0 = (int)y0f, x0 = (int)x0f;
        int   ysr[2] = {y0, y0 + 1};
        int   xsr[2] = {x0, x0 + 1};
        float wy[2] = {1.f - ly, ly};
        float wx[2] = {1.f - lx, lx};
        u16 idx[4]; f16 wgt[4];
#pragma unroll
        for (int r = 0; r < 4; ++r) {
            int yy = ysr[r >> 1], xx = xsr[r & 1];
            bool ok = ((unsigned)yy < HH) && ((unsigned)xx < WW);
            int yc = min(max(yy, 0), HH - 1);
            int xc = min(max(xx, 0), WW - 1);
            idx[r] = (u16)(yc * WW + xc);
            wgt[r] = (f16)(ok ? (wy[r >> 1] * wx[r & 1] * mv) : 0.f);
        }
        uint4 tv;
        tv.x = (u32)idx[0] | ((u32)idx[1] << 16);
        tv.y = (u32)idx[2] | ((u32)idx[3] << 16);
        h2 w01 = {wgt[0], wgt[1]};
        h2 w23 = {wgt[2], wgt[3]};
        tv.z = __builtin_bit_cast(u32, w01);
        tv.w = __builtin_bit_cast(u32, w23);
        STAB[tap][m] = tv;
    }
    __syncthreads();

    if (wv < 8) {
        // ================= consumers: pure MFMA, N=32 slice each =================
        const int fr = lane & 15, q = lane >> 4;
        const int wn = wv << 5;

        f4 acc[8][2];
#pragma unroll
        for (int mi = 0; mi < 8; ++mi) {
            acc[mi][0] = (f4){0.f, 0.f, 0.f, 0.f};
            acc[mi][1] = (f4){0.f, 0.f, 0.f, 0.f};
        }

        for (int kt = 0; kt < NKT; ++kt) {
            const int p = kt & 1;
            BARRIER_RAW();
            frag b0 = *(const frag*)&BsB[p][sw_off(wn + fr, q)];
            frag b1 = *(const frag*)&BsB[p][sw_off(wn + 16 + fr, q)];
#pragma unroll
            for (int mi = 0; mi < 8; ++mi) {
                frag a = *(const frag*)&AsB[p][sw_off(mi * 16 + fr, q)];
                acc[mi][0] = __builtin_amdgcn_mfma_f32_16x16x32_f16(a, b0, acc[mi][0], 0, 0, 0);
                acc[mi][1] = __builtin_amdgcn_mfma_f32_16x16x32_f16(a, b1, acc[mi][1], 0, 0, 0);
            }
        }

        // epilogue: out[b][n][h*64+w]; C/D col=fr(n), row=q*4+r(m)
#pragma unroll
        for (int ni = 0; ni < 2; ++ni) {
            int n_g = wn + ni * 16 + fr;
            float* outn = out + (((size_t)b * COUT + n_g) << 12) + (h0 << 6);
#pragma unroll
            for (int mi = 0; mi < 8; ++mi) {
                int off = ((mi >> 2) << 6) + ((mi & 3) << 4) + (q << 2);
                *(float4*)&outn[off] = make_float4(acc[mi][ni][0], acc[mi][ni][1],
                                                   acc[mi][ni][2], acc[mi][ni][3]);
            }
        }
    } else {
        // ================= producers: gather + packed-f16 interp + staging =========
        const int pt = t - 512;            // 0..511 -> one (m, oct) slot each
        const int mg = pt >> 2, oct = pt & 3;
        const int pwv = wv - 8;            // 0..7
        const int ko_sw = (lane & 3) ^ ((lane >> 3) & 3);  // matches sw_off g
        const u16* xpl = xbf + ((size_t)b << 20);

        auto stageB = [&](int kt, int buf) {
            const u16* src = w2 + ((size_t)kt << 13);
#pragma unroll
            for (int j = 0; j < 2; ++j) {
                int base = (pwv << 5) + (j << 4);
                int n = base + (lane >> 2);
                u16* dst = &BsB[buf][base << 5];  // wave-uniform base
                gl2lds16(src + n * 32 + ko_sw * 8, dst);
            }
        };
        auto loadCorners = [&](int kt, uint4 (&cr)[4]) {
            int tap = kt >> 3;
            int c0 = ((kt & 7) << 5) + (oct << 3);
            uint2 iv = *(const uint2*)&STAB[tap][mg];
            const u16* base = xpl + c0;
            cr[0] = *(const uint4*)(base + ((size_t)(iv.x & 0xFFFFu) << 8));
            cr[1] = *(const uint4*)(base + ((size_t)(iv.x >> 16) << 8));
            cr[2] = *(const uint4*)(base + ((size_t)(iv.y & 0xFFFFu) << 8));
            cr[3] = *(const uint4*)(base + ((size_t)(iv.y >> 16) << 8));
        };
        auto interpStore = [&](int kt, int buf, uint4 (&cr)[4]) {
            int tap = kt >> 3;
            uint2 wvp = *(const uint2*)(((const u32*)&STAB[tap][mg]) + 2);
            h2 w01 = __builtin_bit_cast(h2, wvp.x);
            h2 w23 = __builtin_bit_cast(h2, wvp.y);
            h2 s0 = {w01[0], w01[0]};
            h2 s1 = {w01[1], w01[1]};
            h2 s2 = {w23[0], w23[0]};
            h2 s3 = {w23[1], w23[1]};
            const u32* c0p = (const u32*)&cr[0];
            const u32* c1p = (const u32*)&cr[1];
            const u32* c2p = (const u32*)&cr[2];
            const u32* c3p = (const u32*)&cr[3];
            u32 o[4];
#pragma unroll
            for (int jj = 0; jj < 4; ++jj) {
                h2 v = s0 * __builtin_bit_cast(h2, c0p[jj]);
                v += s1 * __builtin_bit_cast(h2, c1p[jj]);
                v += s2 * __builtin_bit_cast(h2, c2p[jj]);
                v += s3 * __builtin_bit_cast(h2, c3p[jj]);
                o[jj] = __builtin_bit_cast(u32, v);
            }
            *(uint4*)&AsB[buf][sw_off(mg, oct)] = make_uint4(o[0], o[1], o[2], o[3]);
        };

        uint4 cr0[4], cr1[4], cr2[4];      // corners(kt) lives at slot kt%3
        // prologue: B(0)->buf0; corners 0,1,2 in flight; interp(0)->As0
        stageB(0, 0);
        loadCorners(0, cr0);
        loadCorners(1, cr1);
        loadCorners(2, cr2);
        interpStore(0, 0, cr0);
        asm volatile("s_waitcnt lgkmcnt(0)" ::: "memory");

        // pstep(kt, p): entry in-flight (oldest first) = corners(kt+1)[4],
        // B(kt)[2], corners(kt+2)[4]. vmcnt(4) drains corners(kt+1)+B(kt),
        // keeps corners(kt+2) flying; 2-iter slack on corners, 1-iter on B.
        auto pstep = [&](int kt, int p, uint4 (&cur)[4], uint4 (&nxt)[4]) {
            if (kt + 2 < NKT) asm volatile("s_waitcnt vmcnt(4)" ::: "memory");
            else              asm volatile("s_waitcnt vmcnt(0)" ::: "memory");
            BARRIER_RAW();
            if (kt + 1 < NKT) stageB(kt + 1, 1 - p);
            if (kt + 3 < NKT) loadCorners(kt + 3, nxt);
            if (kt + 1 < NKT) interpStore(kt + 1, 1 - p, cur);
            asm volatile("s_waitcnt lgkmcnt(0)" ::: "memory");
        };
        for (int kt = 0; kt < NKT; kt += 6) {
            pstep(kt,     0, cr1, cr0);
            pstep(kt + 1, 1, cr2, cr1);
            pstep(kt + 2, 0, cr0, cr2);
            pstep(kt + 3, 1, cr1, cr0);
            pstep(kt + 4, 0, cr2, cr1);
            pstep(kt + 5, 1, cr0, cr2);
        }
    }
}

extern "C" void kernel_launch(void* const* d_in, const int* in_sizes, int n_in,
                              void* d_out, int out_size, void* d_ws, size_t ws_size,
                              hipStream_t stream) {
    const float* x  = (const float*)d_in[0];
    const float* ow = (const float*)d_in[1];
    const float* ob = (const float*)d_in[2];
    const float* mw = (const float*)d_in[3];
    const float* mb = (const float*)d_in[4];
    const float* rw = (const float*)d_in[5];
    float* out = (float*)d_out;
    char* ws = (char*)d_ws;

    u16*   xbf    = (u16*)(ws + WS_XBF);
    u16*   w2     = (u16*)(ws + WS_W2);
    u16*   w2om   = (u16*)(ws + WS_W2OM);
    float* offmod = (float*)(ws + WS_OFFMOD);

    k_nhwc3<<<dim3(HH, BB), 256, 0, stream>>>(x, xbf);
    k_pack_w2<<<(NKT * COUT * 32 + 255) / 256, 256, 0, stream>>>(rw, w2);
    k_pack_w2om<<<(NKT * 32 * 32 + 255) / 256, 256, 0, stream>>>(ow, mw, w2om);
    k_offmod6<<<dim3(512), 512, 0, stream>>>(xbf, w2om, ob, mb, offmod);
    k_deform8<<<dim3(256), 1024, 0, stream>>>(xbf, offmod, w2, out);
}

// Round 2
// 165.027 us; speedup vs baseline: 1.1137x; 1.0291x over previous
//
#include <hip/hip_runtime.h>
#include <math.h>

#define BB 8
#define CIN 256
#define COUT 256
#define HH 64
#define WW 64
#define OCM 27          // 18 offset + 9 mod channels
#define KTOT 2304       // tap-major: k = tap*256 + c
#define NKT 72          // K-tiles of 32

typedef unsigned int u32;
typedef unsigned short u16;
typedef _Float16 f16;

// ---------------- ws layout (bytes) ----------------
#define WS_XBF 0
#define WS_W2 16777216
#define WS_W2OM 17956864
#define WS_OFFMOD 18104320

__device__ __forceinline__ u16 f2h(float f) {
    f16 h = (f16)f;
    return __builtin_bit_cast(u16, h);
}

typedef __attribute__((address_space(1))) const unsigned int* gptr_t;
typedef __attribute__((address_space(3))) unsigned int* lptr_t;
__device__ __forceinline__ void gl2lds16(const void* g, void* l) {
    __builtin_amdgcn_global_load_lds((gptr_t)g, (lptr_t)l, 16, 0, 0);
}

typedef __attribute__((ext_vector_type(8))) f16 frag;   // 4 VGPR MFMA operand
typedef __attribute__((ext_vector_type(2))) f16 h2;     // packed-half pair
typedef __attribute__((ext_vector_type(4))) float f4;

// Swizzle g(row) = (row>>1)&3: conflict-free (2-way max) for BOTH the
// staging-write phase and the frag-read phase (16 consecutive rows, fixed oct).
__device__ __forceinline__ int sw_off(int row, int oct) {
    return (row << 5) + ((oct ^ ((row >> 1) & 3)) << 3);
}

#define BARRIER_RAW() do { asm volatile("" ::: "memory"); \
    __builtin_amdgcn_s_barrier(); asm volatile("" ::: "memory"); } while (0)

// K0 (fused prep): blockIdx ranges
//   [0,512):    NCHW f32 -> NHWC f16 via LDS transpose (y=bid&63, b=bid>>6)
//   [512,2816): reg_w -> w2 [kt][n][32] f16, k = tap*256+c
//   [2816,3104): offset_w/mod_w -> w2om [kt][32 oc][32 kk] f16
__global__ __launch_bounds__(256) void k_prep(
    const float* __restrict__ x, const float* __restrict__ rw,
    const float* __restrict__ ow, const float* __restrict__ mw,
    u16* __restrict__ xbf, u16* __restrict__ w2, u16* __restrict__ w2om)
{
    const int bid = blockIdx.x;
    const int t = threadIdx.x;
    if (bid < 512) {
        const int y = bid & 63, b = bid >> 6;
        __shared__ float T[64][65];
        const int wl = t & 63, g = t >> 6;
        const int pr = wl & 31, wsub = wl >> 5;   // c-pair, w-subrow for write phase
        u32* xo = (u32*)xbf;
        for (int c0 = 0; c0 < 256; c0 += 64) {
#pragma unroll
            for (int i = 0; i < 16; ++i) {
                int c = g + i * 4;
                T[c][wl] = x[(((size_t)(b * 256 + c0 + c)) << 12) + (y << 6) + wl];
            }
            __syncthreads();
#pragma unroll
            for (int j = 0; j < 8; ++j) {
                int w = j * 8 + g * 2 + wsub;
                u32 v = (u32)f2h(T[2 * pr][w]) | ((u32)f2h(T[2 * pr + 1][w]) << 16);
                xo[((((size_t)b << 12) + (y << 6) + w) << 7) + (c0 >> 1) + pr] = v;
            }
            __syncthreads();
        }
    } else if (bid < 2816) {
        int o = ((bid - 512) << 8) + t;      // exactly NKT*COUT*32 = 589824
        int kk = o & 31;
        int n = (o >> 5) & 255;
        int kt = o >> 13;
        int k = kt * 32 + kk;
        int tap = k >> 8;
        int c = k & 255;
        w2[o] = f2h(rw[n * KTOT + c * 9 + tap]);
    } else {
        int o = ((bid - 2816) << 8) + t;     // exactly NKT*32*32 = 73728
        int kk = o & 31;
        int oc = (o >> 5) & 31;
        int kt = o >> 10;
        int k = kt * 32 + kk;
        int tap = k >> 8;
        int c = k & 255;
        float v = 0.f;
        if (oc < 18) v = ow[oc * KTOT + c * 9 + tap];
        else if (oc < 27) v = mw[(oc - 18) * KTOT + c * 9 + tap];
        w2om[o] = f2h(v);
    }
}

// K1: offset/mod conv, pipelined MFMA, K split across wave-halves. f16 frags.
// grid: 512 linear, b = idx&7 (XCD-local batch), h = idx>>3.
__global__ __launch_bounds__(512, 4) void k_offmod6(
    const u16* __restrict__ xbf, const u16* __restrict__ w2om,
    const float* __restrict__ ob, const float* __restrict__ mb,
    float* __restrict__ offmod)
{
    const int b = blockIdx.x & 7, h = blockIdx.x >> 3;
    const int t = threadIdx.x;
    const int lane = t & 63, wv = t >> 6;
    const int hf = wv >> 2;         // K-half
    const int wl4 = wv & 3;
    const int th = t & 255;
    const int fr = lane & 15, q = lane >> 4;
    const int wm = wl4 << 4;
    const int mg = th >> 2, oct = th & 3;

    __shared__ u16 AsB[2][2][64 * 32];
    __shared__ u16 BsB[2][2][32 * 32];
    __shared__ float red[64][33];

    const u16* xb = xbf + ((size_t)b << 20);
    const int kbase = hf * 36;

    auto loadA = [&](int kt, uint4* r) {
        int tap = kt >> 3;
        int yy = h + tap / 3 - 1, xx = mg + tap % 3 - 1;
        int c0 = ((kt & 7) << 5) + (oct << 3);
        uint4 v = make_uint4(0, 0, 0, 0);
        if ((unsigned)yy < HH && (unsigned)xx < WW)
            v = *(const uint4*)(xb + (((size_t)yy << 6) + xx) * 256 + c0);
        *r = v;
    };
    auto loadB = [&](int kt, uint4* r) {
        if (th < 128) *r = *(const uint4*)(w2om + (size_t)kt * 1024 + (th >> 2) * 32 + (th & 3) * 8);
    };
    auto storeAB = [&](int buf, uint4* rA, uint4* rB) {
        *(uint4*)&AsB[hf][buf][sw_off(mg, oct)] = *rA;
        if (th < 128) *(uint4*)&BsB[hf][buf][sw_off(th >> 2, th & 3)] = *rB;
    };

    f4 acc[2];
    acc[0] = (f4){0.f, 0.f, 0.f, 0.f};
    acc[1] = (f4){0.f, 0.f, 0.f, 0.f};

    uint4 rA0, rB0, rA1, rB1;
    loadA(kbase, &rA0); loadB(kbase, &rB0);
    storeAB(0, &rA0, &rB0);
    loadA(kbase + 1, &rA1); loadB(kbase + 1, &rB1);
    asm volatile("s_waitcnt lgkmcnt(0)" ::: "memory");

    auto body = [&](int i, int p, uint4* cA, uint4* cB, uint4* nA, uint4* nB) {
        BARRIER_RAW();
        frag a  = *(const frag*)&AsB[hf][p][sw_off(wm + fr, q)];
        frag b0 = *(const frag*)&BsB[hf][p][sw_off(fr, q)];
        frag b1 = *(const frag*)&BsB[hf][p][sw_off(16 + fr, q)];
        if (i + 2 < 36) { loadA(kbase + i + 2, nA); loadB(kbase + i + 2, nB); }
        if (i + 1 < 36) storeAB(1 - p, cA, cB);
        acc[0] = __builtin_amdgcn_mfma_f32_16x16x32_f16(a, b0, acc[0], 0, 0, 0);
        acc[1] = __builtin_amdgcn_mfma_f32_16x16x32_f16(a, b1, acc[1], 0, 0, 0);
        asm volatile("s_waitcnt lgkmcnt(0)" ::: "memory");
    };
    for (int i = 0; i < 36; i += 2) {
        body(i, 0, &rA1, &rB1, &rA0, &rB0);
        body(i + 1, 1, &rA0, &rB0, &rA1, &rB1);
    }

    // ---- K-half reduction ----
    if (hf == 1) {
#pragma unroll
        for (int ni = 0; ni < 2; ++ni)
#pragma unroll
            for (int r = 0; r < 4; ++r)
                red[wm + q * 4 + r][ni * 16 + fr] = acc[ni][r];
    }
    __syncthreads();
    if (hf == 0) {
#pragma unroll
        for (int ni = 0; ni < 2; ++ni) {
            int oc = ni * 16 + fr;
            if (oc >= OCM) continue;
            bool is_off = oc < 18;
            float bias = is_off ? ob[oc] : mb[oc - 18];
            float4 v;
            float* vp = (float*)&v;
#pragma unroll
            for (int r = 0; r < 4; ++r) {
                float s = acc[ni][r] + red[wm + q * 4 + r][oc] + bias;
                vp[r] = is_off ? fminf(fmaxf(s, -16.f), 16.f)
                               : 1.f / (1.f + __expf(-s));
            }
            *(float4*)&offmod[(((size_t)b * OCM + oc) << 12) + (h << 6) + wm + q * 4] = v;
        }
    }
}

// K2: deformable conv, M=128 (2 h-rows), 8 consumer + 8 producer waves,
// 64x64 consumer wave tiles (2M x 4N), setprio around MFMA cluster,
// f16 packed interp, packed sample table, distance-3 corner prefetch.
// grid: 256 linear, b = idx&7 (XCD-local batch), hpair = idx>>3.
__global__ __launch_bounds__(1024, 4) void k_deform9(
    const u16* __restrict__ xbf, const float* __restrict__ offmod,
    const u16* __restrict__ w2, float* __restrict__ out)
{
    const int t = threadIdx.x;
    const int b = blockIdx.x & 7, hp = blockIdx.x >> 3;
    const int h0 = hp << 1;
    const int lane = t & 63, wv = t >> 6;

    __shared__ uint4 STAB[9][128];      // {idx0..3 (u16), w0..3 (f16)} per (tap,m)
    __shared__ u16 AsB[2][128 * 32];
    __shared__ u16 BsB[2][256 * 32];

    // ---- sample tables: 9 taps x 128 m (all 1024 threads) ----
    const float* om = offmod + (size_t)b * OCM * 4096;
    for (int e = t; e < 9 * 128; e += 1024) {
        int m = e & 127, tap = e >> 7;
        int hh = h0 + (m >> 6), ww = m & 63;
        float dy = om[(tap * 2) * 4096 + hh * 64 + ww];
        float dx = om[(tap * 2 + 1) * 4096 + hh * 64 + ww];
        float mv = om[(18 + tap) * 4096 + hh * 64 + ww];
        float py = dy + (float)(tap / 3) + (float)(hh - 1);
        float px = dx + (float)(tap % 3) + (float)(ww - 1);
        float y0f = floorf(py), x0f = floorf(px);
        float ly = py - y0f, lx = px - x0f;
        int y0 = (int)y0f, x0 = (int)x0f;
        int   ysr[2] = {y0, y0 + 1};
        int   xsr[2] = {x0, x0 + 1};
        float wy[2] = {1.f - ly, ly};
        float wx[2] = {1.f - lx, lx};
        u16 idx[4]; f16 wgt[4];
#pragma unroll
        for (int r = 0; r < 4; ++r) {
            int yy = ysr[r >> 1], xx = xsr[r & 1];
            bool ok = ((unsigned)yy < HH) && ((unsigned)xx < WW);
            int yc = min(max(yy, 0), HH - 1);
            int xc = min(max(xx, 0), WW - 1);
            idx[r] = (u16)(yc * WW + xc);
            wgt[r] = (f16)(ok ? (wy[r >> 1] * wx[r & 1] * mv) : 0.f);
        }
        uint4 tv;
        tv.x = (u32)idx[0] | ((u32)idx[1] << 16);
        tv.y = (u32)idx[2] | ((u32)idx[3] << 16);
        h2 w01 = {wgt[0], wgt[1]};
        h2 w23 = {wgt[2], wgt[3]};
        tv.z = __builtin_bit_cast(u32, w01);
        tv.w = __builtin_bit_cast(u32, w23);
        STAB[tap][m] = tv;
    }
    __syncthreads();

    if (wv < 8) {
        // ========= consumers: pure MFMA, 64x64 wave tile (2M x 4N grid) =========
        const int fr = lane & 15, q = lane >> 4;
        const int wn4 = wv & 3;          // N quarter (64 cols)
        const int wm2 = wv >> 2;         // M half (64 rows = one h row)

        f4 acc[4][4];
#pragma unroll
        for (int mi = 0; mi < 4; ++mi)
#pragma unroll
            for (int ni = 0; ni < 4; ++ni) acc[mi][ni] = (f4){0.f, 0.f, 0.f, 0.f};

        for (int kt = 0; kt < NKT; ++kt) {
            const int p = kt & 1;
            BARRIER_RAW();
            frag av[4], bv[4];
#pragma unroll
            for (int mi = 0; mi < 4; ++mi)
                av[mi] = *(const frag*)&AsB[p][sw_off((wm2 << 6) + mi * 16 + fr, q)];
#pragma unroll
            for (int ni = 0; ni < 4; ++ni)
                bv[ni] = *(const frag*)&BsB[p][sw_off((wn4 << 6) + ni * 16 + fr, q)];
            __builtin_amdgcn_s_setprio(1);
#pragma unroll
            for (int mi = 0; mi < 4; ++mi)
#pragma unroll
                for (int ni = 0; ni < 4; ++ni)
                    acc[mi][ni] = __builtin_amdgcn_mfma_f32_16x16x32_f16(
                        av[mi], bv[ni], acc[mi][ni], 0, 0, 0);
            __builtin_amdgcn_s_setprio(0);
        }

        // epilogue: out[b][n][(h0+wm2)*64 + w]; C/D col=fr(n), row=q*4+r(m)
#pragma unroll
        for (int ni = 0; ni < 4; ++ni) {
            int n_g = (wn4 << 6) + ni * 16 + fr;
            float* outn = out + (((size_t)b * COUT + n_g) << 12) + ((h0 + wm2) << 6);
#pragma unroll
            for (int mi = 0; mi < 4; ++mi) {
                *(float4*)&outn[mi * 16 + (q << 2)] =
                    make_float4(acc[mi][ni][0], acc[mi][ni][1],
                                acc[mi][ni][2], acc[mi][ni][3]);
            }
        }
    } else {
        // ================= producers: gather + packed-f16 interp + staging =========
        const int pt = t - 512;            // 0..511 -> one (m, oct) slot each
        const int mg = pt >> 2, oct = pt & 3;
        const int pwv = wv - 8;            // 0..7
        const int ko_sw = (lane & 3) ^ ((lane >> 3) & 3);  // matches sw_off g
        const u16* xpl = xbf + ((size_t)b << 20);

        auto stageB = [&](int kt, int buf) {
            const u16* src = w2 + ((size_t)kt << 13);
#pragma unroll
            for (int j = 0; j < 2; ++j) {
                int base = (pwv << 5) + (j << 4);
                int n = base + (lane >> 2);
                u16* dst = &BsB[buf][base << 5];  // wave-uniform base
                gl2lds16(src + n * 32 + ko_sw * 8, dst);
            }
        };
        auto loadCorners = [&](int kt, uint4 (&cr)[4]) {
            int tap = kt >> 3;
            int c0 = ((kt & 7) << 5) + (oct << 3);
            uint2 iv = *(const uint2*)&STAB[tap][mg];
            const u16* base = xpl + c0;
            cr[0] = *(const uint4*)(base + ((size_t)(iv.x & 0xFFFFu) << 8));
            cr[1] = *(const uint4*)(base + ((size_t)(iv.x >> 16) << 8));
            cr[2] = *(const uint4*)(base + ((size_t)(iv.y & 0xFFFFu) << 8));
            cr[3] = *(const uint4*)(base + ((size_t)(iv.y >> 16) << 8));
        };
        auto interpStore = [&](int kt, int buf, uint4 (&cr)[4]) {
            int tap = kt >> 3;
            uint2 wvp = *(const uint2*)(((const u32*)&STAB[tap][mg]) + 2);
            h2 w01 = __builtin_bit_cast(h2, wvp.x);
            h2 w23 = __builtin_bit_cast(h2, wvp.y);
            h2 s0 = {w01[0], w01[0]};
            h2 s1 = {w01[1], w01[1]};
            h2 s2 = {w23[0], w23[0]};
            h2 s3 = {w23[1], w23[1]};
            const u32* c0p = (const u32*)&cr[0];
            const u32* c1p = (const u32*)&cr[1];
            const u32* c2p = (const u32*)&cr[2];
            const u32* c3p = (const u32*)&cr[3];
            u32 o[4];
#pragma unroll
            for (int jj = 0; jj < 4; ++jj) {
                h2 v = s0 * __builtin_bit_cast(h2, c0p[jj]);
                v += s1 * __builtin_bit_cast(h2, c1p[jj]);
                v += s2 * __builtin_bit_cast(h2, c2p[jj]);
                v += s3 * __builtin_bit_cast(h2, c3p[jj]);
                o[jj] = __builtin_bit_cast(u32, v);
            }
            *(uint4*)&AsB[buf][sw_off(mg, oct)] = make_uint4(o[0], o[1], o[2], o[3]);
        };

        uint4 cr0[4], cr1[4], cr2[4];      // corners(kt) lives at slot kt%3
        // prologue: B(0)->buf0; corners 0,1,2 in flight; interp(0)->As0
        stageB(0, 0);
        loadCorners(0, cr0);
        loadCorners(1, cr1);
        loadCorners(2, cr2);
        interpStore(0, 0, cr0);
        asm volatile("s_waitcnt lgkmcnt(0)" ::: "memory");

        // pstep(kt, p): entry in-flight (oldest first) = corners(kt+1)[4],
        // B(kt)[2], corners(kt+2)[4]. vmcnt(4) drains corners(kt+1)+B(kt),
        // keeps corners(kt+2) flying; 2-iter slack on corners, 1-iter on B.
        auto pstep = [&](int kt, int p, uint4 (&cur)[4], uint4 (&nxt)[4]) {
            if (kt + 2 < NKT) asm volatile("s_waitcnt vmcnt(4)" ::: "memory");
            else              asm volatile("s_waitcnt vmcnt(0)" ::: "memory");
            BARRIER_RAW();
            if (kt + 1 < NKT) stageB(kt + 1, 1 - p);
            if (kt + 3 < NKT) loadCorners(kt + 3, nxt);
            if (kt + 1 < NKT) interpStore(kt + 1, 1 - p, cur);
            asm volatile("s_waitcnt lgkmcnt(0)" ::: "memory");
        };
        for (int kt = 0; kt < NKT; kt += 6) {
            pstep(kt,     0, cr1, cr0);
            pstep(kt + 1, 1, cr2, cr1);
            pstep(kt + 2, 0, cr0, cr2);
            pstep(kt + 3, 1, cr1, cr0);
            pstep(kt + 4, 0, cr2, cr1);
            pstep(kt + 5, 1, cr0, cr2);
        }
    }
}

extern "C" void kernel_launch(void* const* d_in, const int* in_sizes, int n_in,
                              void* d_out, int out_size, void* d_ws, size_t ws_size,
                              hipStream_t stream) {
    const float* x  = (const float*)d_in[0];
    const float* ow = (const float*)d_in[1];
    const float* ob = (const float*)d_in[2];
    const float* mw = (const float*)d_in[3];
    const float* mb = (const float*)d_in[4];
    const float* rw = (const float*)d_in[5];
    float* out = (float*)d_out;
    char* ws = (char*)d_ws;

    u16*   xbf    = (u16*)(ws + WS_XBF);
    u16*   w2     = (u16*)(ws + WS_W2);
    u16*   w2om   = (u16*)(ws + WS_W2OM);
    float* offmod = (float*)(ws + WS_OFFMOD);

    k_prep<<<dim3(3104), 256, 0, stream>>>(x, rw, ow, mw, xbf, w2, w2om);
    k_offmod6<<<dim3(512), 512, 0, stream>>>(xbf, w2om, ob, mb, offmod);
    k_deform9<<<dim3(256), 1024, 0, stream>>>(xbf, offmod, w2, out);
}